// Round 10
// baseline (385.115 us; speedup 1.0000x reference)
//
#include <hip/hip_runtime.h>
#include <hip/hip_bf16.h>
#include <stdint.h>

#define IN_F 1024
#define OUT_F 1024
#define NB 8
#define KDIM (IN_F + IN_F * NB)  /* 9216 */
#define NROWS 4096
#define SLICE_ELEMS (NROWS * OUT_F)
#define PREP_BLOCKS ((NROWS * IN_F) / 256)        /* 16384 */
#define WCONV_BLOCKS ((OUT_F * KDIM) / (4 * 256)) /* 9216  */
#define SPLIT 2
#define KSLICE (KDIM / SPLIT) /* 4608 */

// s_waitcnt immediates (gfx9 layout: vm lo[3:0], exp[6:4], lgkm[11:8], vm hi[15:14]).
// Don't-care fields set to max so a field-width mismatch errs toward "no wait" on
// the unused counter, never toward skipping the needed one.
#define WAIT_VM32 0x8F70
#define WAIT_VM16 0x4F70
#define WAIT_VM0 0x0F70
#define WAIT_LGKM0 0xC07F

typedef __attribute__((ext_vector_type(8))) short bf16x8;
typedef __attribute__((ext_vector_type(4))) short bf16x4;
typedef __attribute__((ext_vector_type(4))) float f32x4;

#define AS1 const __attribute__((address_space(1))) void*
#define AS3 __attribute__((address_space(3))) void*

// Closed-form uniform cubic B-spline (knots t_j = -2.2 + 0.4j; EPS=1e-8 shift is
// far below bf16 rounding). For x in [t_i,t_{i+1}): 4 nonzero cardinal cubics.
__device__ __forceinline__ void bspline8(float x, float b8[8]) {
  float u = (x + 2.2f) * 2.5f;  // (x - t0)/h
  bool in = (u >= 0.0f) && (u < 11.0f);
  float uc = fminf(fmaxf(u, 0.0f), 10.99f);
  int i = (int)uc;
  float f = uc - (float)i;
  float g = 1.0f - f;
  float f2 = f * f, f3 = f2 * f;
  const float s = 1.0f / 6.0f;
  float v0 = f3 * s;
  float v1 = (-3.0f * f3 + 3.0f * f2 + 3.0f * f + 1.0f) * s;
  float v2 = (3.0f * f3 - 6.0f * f2 + 4.0f) * s;
  float v3 = g * g * g * s;
#pragma unroll
  for (int j = 0; j < 8; ++j) {
    int d = i - j;
    float r = (d == 0) ? v0 : (d == 1) ? v1 : (d == 2) ? v2 : (d == 3) ? v3 : 0.0f;
    b8[j] = in ? r : 0.0f;
  }
}

// A := [silu(x) | bspline(x)] bf16, W := [bw | sw] bf16. One launch, branch on blockIdx.
__global__ void prep_all_kernel(const float* __restrict__ x, const float* __restrict__ bw,
                                const float* __restrict__ sw, __hip_bfloat16* __restrict__ A,
                                __hip_bfloat16* __restrict__ W) {
  if (blockIdx.x < PREP_BLOCKS) {
    int idx = blockIdx.x * 256 + threadIdx.x;
    int n = idx >> 10;
    int i = idx & 1023;
    float xv = x[idx];
    float sl = xv / (1.0f + __expf(-xv));
    __hip_bfloat16* row = A + (size_t)n * KDIM;
    row[i] = __float2bfloat16(sl);
    float b8[8];
    bspline8(xv, b8);
    alignas(16) __hip_bfloat16 tmp[8];
#pragma unroll
    for (int c = 0; c < 8; ++c) tmp[c] = __float2bfloat16(b8[c]);
    *(bf16x8*)(row + IN_F + i * 8) = *(const bf16x8*)tmp;
  } else {
    int v = (blockIdx.x - PREP_BLOCKS) * 256 + threadIdx.x;
    int e = v * 4;
    int o = e / KDIM;
    int k = e - o * KDIM;
    float4 val = (k < IN_F) ? *(const float4*)(bw + o * IN_F + k)
                            : *(const float4*)(sw + (size_t)o * (IN_F * NB) + (k - IN_F));
    alignas(8) __hip_bfloat16 t[4];
    t[0] = __float2bfloat16(val.x);
    t[1] = __float2bfloat16(val.y);
    t[2] = __float2bfloat16(val.z);
    t[3] = __float2bfloat16(val.w);
    *(bf16x4*)(W + e) = *(const bf16x4*)t;
  }
}

// Producer/consumer GEMM: dst[z] = A @ W^T over K-slice z. 128x128 tile, BK=32.
// NO __syncthreads in the K-loop (the vmcnt(0)-before-s_barrier drain was the
// plateau, rounds 1-9). Wave 4 = producer: keeps 3 slots (48 global_load_lds) in
// flight, s_waitcnt vmcnt(32) retires the oldest slot (in-order, m135), then
// publishes an LDS ready-flag. Waves 0-3 = consumers: poll ready, ds_read frags,
// MFMA, ack done-flag; their only waits are compiler fine-grained lgkmcnt.
// Ring: 4 slots x (8KB A + 8KB B) = 64 KB -> 2 blocks/CU. Slot layout: 8 groups
// of 16 rows in MFMA fragment order (lane l: row=l&15, kchunk=l>>4) -> addr =
// wave-uniform base + 16B*lane (conflict-free; legal global_load_lds scatter).
__global__ __launch_bounds__(320) void gemm_pc(const __hip_bfloat16* __restrict__ A,
                                               const __hip_bfloat16* __restrict__ W,
                                               float* __restrict__ dst) {
  __shared__ __align__(16) __hip_bfloat16 sbuf[4][2][4096];  // [slot][A=0/B=1][128*32]
  __shared__ int ready[4];
  __shared__ int done[4][4];  // [slot][consumer wave]
  const int tid = threadIdx.x;
  const int wave = tid >> 6;
  const int lane = tid & 63;
  const int bm = blockIdx.x * 128;
  const int bn = blockIdx.y * 128;
  const int kbeg = blockIdx.z * KSLICE;
  const int iters = KSLICE / 32;  // 144

  if (tid < 4) ready[tid] = 0;
  if (tid < 16) ((int*)done)[tid] = 0;
  __syncthreads();  // the only block-wide barrier (flag init)

  if (wave == 4) {
    // ---------------- producer ----------------
    const int srow = lane & 15;
    const int skc = (lane >> 4) * 8;
    const __hip_bfloat16* baseA = A + (size_t)(bm + srow) * KDIM + kbeg + skc;
    const __hip_bfloat16* baseB = W + (size_t)(bn + srow) * KDIM + kbeg + skc;
    int issued = 0, flagged = 0;
    while (flagged < iters) {
      while (issued < iters && issued - flagged < 3) {
        const int s = issued & 3;
        if (issued >= 4) {
          const int need = issued - 3;  // consumers finished iter issued-4 on slot s
          while (true) {
            int m0 = ((volatile int*)done)[s * 4 + 0];
            int m1 = ((volatile int*)done)[s * 4 + 1];
            int m2 = ((volatile int*)done)[s * 4 + 2];
            int m3 = ((volatile int*)done)[s * 4 + 3];
            if (m0 >= need && m1 >= need && m2 >= need && m3 >= need) break;
            __builtin_amdgcn_s_sleep(1);
          }
        }
        const int koff = issued * 32;
#pragma unroll
        for (int g = 0; g < 8; ++g) {
          __builtin_amdgcn_global_load_lds((AS1)(baseA + (size_t)g * 16 * KDIM + koff),
                                           (AS3)(&sbuf[s][0][g * 512]), 16, 0, 0);
          __builtin_amdgcn_global_load_lds((AS1)(baseB + (size_t)g * 16 * KDIM + koff),
                                           (AS3)(&sbuf[s][1][g * 512]), 16, 0, 0);
        }
        ++issued;
      }
      const int inflight = issued - flagged;
      if (inflight >= 3)
        __builtin_amdgcn_s_waitcnt(WAIT_VM32);  // oldest 16 (slot `flagged`) retired
      else if (inflight == 2)
        __builtin_amdgcn_s_waitcnt(WAIT_VM16);
      else
        __builtin_amdgcn_s_waitcnt(WAIT_VM0);
      if (lane == 0) ((volatile int*)ready)[flagged & 3] = flagged + 1;
      ++flagged;
    }
  } else {
    // ---------------- consumers ----------------
    const int wm = (wave & 1) * 64;
    const int wn = (wave >> 1) * 64;
    const int r = lane & 15;
    const int quad = lane >> 4;
    f32x4 acc[4][4];
#pragma unroll
    for (int a = 0; a < 4; ++a)
#pragma unroll
      for (int b = 0; b < 4; ++b) acc[a][b] = (f32x4){0.f, 0.f, 0.f, 0.f};

    for (int k = 0; k < iters; ++k) {
      const int s = k & 3;
      while (((volatile int*)ready)[s] < k + 1) __builtin_amdgcn_s_sleep(1);
      bf16x8 af[4], bfr[4];
#pragma unroll
      for (int t = 0; t < 4; ++t) {
        af[t] = *(const bf16x8*)&sbuf[s][0][((wm >> 4) + t) * 512 + lane * 8];
        bfr[t] = *(const bf16x8*)&sbuf[s][1][((wn >> 4) + t) * 512 + lane * 8];
      }
#pragma unroll
      for (int tm = 0; tm < 4; ++tm)
#pragma unroll
        for (int tn = 0; tn < 4; ++tn)
          acc[tm][tn] =
              __builtin_amdgcn_mfma_f32_16x16x32_bf16(af[tm], bfr[tn], acc[tm][tn], 0, 0, 0);
      // Fence: frag ds_reads retired before the ack is visible (intrinsic has side
      // effects -> loads can't sink below it, volatile store can't rise above it).
      __builtin_amdgcn_s_waitcnt(WAIT_LGKM0);
      if (lane == 0) ((volatile int*)done)[s * 4 + wave] = k + 1;
    }

    // C/D map: col=lane&15, row=quad*4+reg (m89-verified). Plain stores.
    float* __restrict__ d = dst + (size_t)blockIdx.z * SLICE_ELEMS;
#pragma unroll
    for (int tm = 0; tm < 4; ++tm) {
#pragma unroll
      for (int tn = 0; tn < 4; ++tn) {
        const int col = bn + wn + tn * 16 + r;
#pragma unroll
        for (int reg = 0; reg < 4; ++reg) {
          const int rowi = bm + wm + tm * 16 + quad * 4 + reg;
          d[(size_t)rowi * OUT_F + col] = acc[tm][tn][reg];
        }
      }
    }
  }
}

// out = bias + sum_s P[s], float4 per thread.
__global__ void reduce_kernel(const float* __restrict__ P, const float* __restrict__ bias,
                              float* __restrict__ out, int S) {
  int v = blockIdx.x * 256 + threadIdx.x;
  int e = v * 4;
  int o = e & (OUT_F - 1);
  float4 acc = *(const float4*)(bias + o);
  for (int s = 0; s < S; ++s) {
    float4 p = *(const float4*)(P + (size_t)s * SLICE_ELEMS + e);
    acc.x += p.x;
    acc.y += p.y;
    acc.z += p.z;
    acc.w += p.w;
  }
  *(float4*)(out + e) = acc;
}

// Emergency fallback if ws is too small for A+W+P (fp32, slow but correct).
__global__ void kan_fallback(const float* __restrict__ x, const float* __restrict__ bw,
                             const float* __restrict__ bb, const float* __restrict__ sw,
                             float* __restrict__ out) {
  __shared__ float act[KDIM];
  int n = blockIdx.x;
  for (int i = threadIdx.x; i < IN_F; i += 256) {
    float xv = x[(size_t)n * IN_F + i];
    act[i] = xv / (1.0f + __expf(-xv));
    float b8[8];
    bspline8(xv, b8);
#pragma unroll
    for (int c = 0; c < 8; ++c) act[IN_F + i * 8 + c] = b8[c];
  }
  __syncthreads();
  for (int o = threadIdx.x; o < OUT_F; o += 256) {
    float s = bb[o];
    const float* wbp = bw + (size_t)o * IN_F;
    for (int k = 0; k < IN_F; ++k) s += act[k] * wbp[k];
    const float* wsp = sw + (size_t)o * (IN_F * NB);
    for (int k = 0; k < IN_F * NB; ++k) s += act[IN_F + k] * wsp[k];
    out[(size_t)n * OUT_F + o] = s;
  }
}

extern "C" void kernel_launch(void* const* d_in, const int* in_sizes, int n_in, void* d_out,
                              int out_size, void* d_ws, size_t ws_size, hipStream_t stream) {
  const float* x = (const float*)d_in[0];
  const float* bw = (const float*)d_in[1];
  const float* bb = (const float*)d_in[2];
  const float* sw = (const float*)d_in[3];
  float* out = (float*)d_out;

  const size_t needA = (size_t)NROWS * KDIM * 2;  // 75.5 MB
  const size_t needW = (size_t)OUT_F * KDIM * 2;  // 18.9 MB
  const size_t sliceB = (size_t)SLICE_ELEMS * 4;  // 16.8 MB
  if (ws_size < needA + needW + SPLIT * sliceB) {
    kan_fallback<<<NROWS, 256, 0, stream>>>(x, bw, bb, sw, out);
    return;
  }
  __hip_bfloat16* A = (__hip_bfloat16*)d_ws;
  __hip_bfloat16* W = (__hip_bfloat16*)((char*)d_ws + needA);
  float* P = (float*)((char*)d_ws + needA + needW);

  prep_all_kernel<<<PREP_BLOCKS + WCONV_BLOCKS, 256, 0, stream>>>(x, bw, sw, A, W);
  gemm_pc<<<dim3(NROWS / 128, OUT_F / 128, SPLIT), 320, 0, stream>>>(A, W, P);
  reduce_kernel<<<SLICE_ELEMS / (4 * 256), 256, 0, stream>>>(P, bb, out, SPLIT);
}